// Round 9
// baseline (293.003 us; speedup 1.0000x reference)
//
#include <hip/hip_runtime.h>

// Problem constants (B=2, S=4096, D=512, H=8, Dh=64). f32 I/O, bf16 MFMA inside.
#define MTOT 8192  // B*S

typedef __attribute__((ext_vector_type(8))) short bf16x8;
typedef __attribute__((ext_vector_type(4))) float f32x4;

#if __has_builtin(__builtin_amdgcn_exp2f)
#define EXP2F __builtin_amdgcn_exp2f
#else
#define EXP2F exp2f
#endif

#define SC 0.18033688011112042f  // (1/8) * log2(e), folded into K
#define LDP 72                   // bf16 LDS row stride: 36 dw == 4 mod 32
#define CTS 136                  // gemm epilogue C-tile stride (el)
#define MOS 68                   // f32 merge-buffer stride: 68 == 4 mod 32

static __device__ __forceinline__ unsigned short tb(float f) {
  union { float f; unsigned int i; } x;
  x.f = f;
  return (unsigned short)(x.i >> 16);
}
static __device__ __forceinline__ unsigned int pkt(float a, float b) {
  union { float f; unsigned int i; } xa, xb;
  xa.f = a; xb.f = b;
  return (xa.i >> 16) | (xb.i & 0xFFFF0000u);
}
static __device__ __forceinline__ bf16x8 ld8f32_bf16(const float* __restrict__ p) {
  f32x4 lo = *(const f32x4*)p;
  f32x4 hi = *(const f32x4*)(p + 4);
  union { unsigned int u[4]; bf16x8 v; } r;
  r.u[0] = pkt(lo[0], lo[1]);
  r.u[1] = pkt(lo[2], lo[3]);
  r.u[2] = pkt(hi[0], hi[1]);
  r.u[3] = pkt(hi[2], hi[3]);
  return r.v;
}
static __device__ __forceinline__ bf16x8 comb64(uint2 lo, uint2 hi) {
  union { uint2 p[2]; bf16x8 v; } r;
  r.p[0] = lo; r.p[1] = hi;
  return r.v;
}

// ---------------------------------------------------------------------------
// Kernel 1: projection GEMM, LDS-staged, register-prefetch pipelined.
// Columns: [0,512) Q -> Q_ws[bh][s][dh]; [512,1024) V -> Vt_ws[bh][dh][s];
//          [1024,1536) K (*SC) -> K_ws[bh][s][dh] (only when nct==12).
// ---------------------------------------------------------------------------
__global__ __launch_bounds__(256) void gemm_qvk(
    const float* __restrict__ mf,
    const float* __restrict__ Wc,
    const float* __restrict__ bc,
    const float* __restrict__ Wv,
    const float* __restrict__ bv,
    unsigned short* __restrict__ ws,
    int nct)
{
  const int bid = blockIdx.x;
  const int tn = bid % nct, tm = bid / nct;
  const int w = threadIdx.x >> 6, lane = threadIdx.x & 63;
  const int n = lane & 15, q = lane >> 4;

  __shared__ alignas(16) unsigned short smem[2 * 128 * LDP];  // As | Bs; Ct overlay
  unsigned short* As = smem;
  unsigned short* Bs = smem + 128 * LDP;

  f32x4 acc[4][4] = {};
  const int rowA0 = tm * 128, colB0 = tn * 128;
  const int sr = threadIdx.x >> 4;           // staging row 0..15
  const int sc4 = (threadIdx.x & 15) * 4;    // f32 col offset (16B)

  // Preload chunk 0 into registers.
  f32x4 avr[8], bvr[8];
#pragma unroll
  for (int rr = 0; rr < 8; ++rr) {
    const int row = rr * 16 + sr;
    avr[rr] = *(const f32x4*)(mf + (size_t)(rowA0 + row) * 512 + sc4);
    const int cB = colB0 + row;
    const float* bsrc = (cB < 1024) ? (Wc + (size_t)cB * 512)
                                    : (Wv + (size_t)(cB - 1024) * 512);
    bvr[rr] = *(const f32x4*)(bsrc + sc4);
  }

  for (int kc = 0; kc < 512; kc += 64) {
    __syncthreads();   // previous chunk's frag reads done
#pragma unroll
    for (int rr = 0; rr < 8; ++rr) {
      const int row = rr * 16 + sr;
      uint2 ap; ap.x = pkt(avr[rr][0], avr[rr][1]); ap.y = pkt(avr[rr][2], avr[rr][3]);
      *(uint2*)(&As[row * LDP + sc4]) = ap;
      uint2 bp; bp.x = pkt(bvr[rr][0], bvr[rr][1]); bp.y = pkt(bvr[rr][2], bvr[rr][3]);
      *(uint2*)(&Bs[row * LDP + sc4]) = bp;
    }
    __syncthreads();
    // Issue next chunk's loads NOW; latency hides behind the 32 MFMAs below.
    if (kc + 64 < 512) {
      const int kn = kc + 64;
#pragma unroll
      for (int rr = 0; rr < 8; ++rr) {
        const int row = rr * 16 + sr;
        avr[rr] = *(const f32x4*)(mf + (size_t)(rowA0 + row) * 512 + kn + sc4);
        const int cB = colB0 + row;
        const float* bsrc = (cB < 1024) ? (Wc + (size_t)cB * 512)
                                        : (Wv + (size_t)(cB - 1024) * 512);
        bvr[rr] = *(const f32x4*)(bsrc + kn + sc4);
      }
    }
#pragma unroll
    for (int ks = 0; ks < 2; ++ks) {
      bf16x8 a[4], b[4];
#pragma unroll
      for (int si = 0; si < 4; ++si)
        a[si] = *(const bf16x8*)(&As[((w >> 1) * 64 + si * 16 + n) * LDP + ks * 32 + q * 8]);
#pragma unroll
      for (int sj = 0; sj < 4; ++sj)
        b[sj] = *(const bf16x8*)(&Bs[((w & 1) * 64 + sj * 16 + n) * LDP + ks * 32 + q * 8]);
#pragma unroll
      for (int si = 0; si < 4; ++si)
#pragma unroll
        for (int sj = 0; sj < 4; ++sj)
          acc[si][sj] = __builtin_amdgcn_mfma_f32_16x16x32_bf16(a[si], b[sj], acc[si][sj], 0, 0, 0);
    }
  }

  // ---- epilogue: LDS transpose (Ct overlays As/Bs) then coalesced stores ----
  __syncthreads();
  unsigned short* Ct = smem;  // [128][CTS]
  const bool isV = (tn >= 4 && tn < 8);
  const int rl0 = (w >> 1) * 64, cl0 = (w & 1) * 64;

  if (!isV) {
    const bool isK = (tn >= 8);
#pragma unroll
    for (int sj = 0; sj < 4; ++sj) {
      const int c = colB0 + sj * 16 + n;
      const float bias = isK ? bv[c - 1024] : bc[c];
#pragma unroll
      for (int si = 0; si < 4; ++si)
#pragma unroll
        for (int r = 0; r < 4; ++r) {
          float v = acc[si][sj][r] + bias;
          if (isK) v *= SC;
          Ct[(rl0 + si * 16 + q * 4 + r) * CTS + cl0 + sj * 16 + n] = tb(v);
        }
    }
  } else {
#pragma unroll
    for (int sj = 0; sj < 4; ++sj) {
      const float bias = bc[colB0 + sj * 16 + n];
#pragma unroll
      for (int si = 0; si < 4; ++si) {
        uint2 pk;
        pk.x = pkt(acc[si][sj][0] + bias, acc[si][sj][1] + bias);
        pk.y = pkt(acc[si][sj][2] + bias, acc[si][sj][3] + bias);
        *(uint2*)(&Ct[(cl0 + sj * 16 + n) * CTS + rl0 + si * 16 + q * 4]) = pk;
      }
    }
  }
  __syncthreads();

  const int rk = threadIdx.x & 7, rr2 = threadIdx.x >> 3;
#pragma unroll
  for (int rp = 0; rp < 4; ++rp) {
    const int row = rp * 32 + rr2;
#pragma unroll
    for (int ch = 0; ch < 2; ++ch) {
      const int col = ch * 64 + rk * 8;
      bf16x8 v = *(const bf16x8*)(&Ct[row * CTS + col]);
      if (!isV) {
        const int srow = rowA0 + row;
        const int bb = srow >> 12, ss = srow & 4095;
        const int cg = colB0 + col;
        const int cl = (cg >= 1024) ? (cg - 1024) : cg;
        const int hh = cl >> 6, dh0 = cl & 63;
        unsigned short* base = (cg >= 1024) ? (ws + (size_t)2 * MTOT * 512) : ws;
        *(bf16x8*)(base + ((size_t)((bb * 8 + hh) * 4096 + ss)) * 64 + dh0) = v;
      } else {
        const int cv = (tn - 4) * 128 + row;
        const int hh = cv >> 6, dh0 = cv & 63;
        const int sg = rowA0 + col;
        const int bb = sg >> 12, ss = sg & 4095;
        *(bf16x8*)(ws + (size_t)MTOT * 512 +
                   ((size_t)((bb * 8 + hh) * 64 + dh0)) * 4096 + ss) = v;
      }
    }
  }
}

// ---------------------------------------------------------------------------
// Kernel 2: flash attention, pure-register j-loop (no LDS, no barriers).
// P stays in registers: QK's transposed C-layout (lane holds S[j][i=lane&15])
// is repacked in-register into the PV A-fragment under a permuted k-order
// pi_s(q*8+e); V^T B-frags load the SAME permuted j order as two b64s.
// Since both operands agree slot-for-slot, the j-sum is exact.
// ---------------------------------------------------------------------------
template <bool KWS>
__global__ __launch_bounds__(128, 2) void attn_kernel(
    const unsigned short* __restrict__ qvws,
    const float* __restrict__ mf,
    const float* __restrict__ Wv,
    const float* __restrict__ bv,
    float* __restrict__ out)
{
  const int bid = blockIdx.x;
  const int bh = ((bid & 7) << 1) | ((bid >> 3) & 1);  // XCD-local bh pairing
  const int ib = bid >> 4;
  const int b_ = bh >> 3, h = bh & 7;
  const int w = threadIdx.x >> 6, lane = threadIdx.x & 63;
  const int n = lane & 15, q = lane >> 4;
  const int i0 = ib * 64;

  __shared__ alignas(16) float mO[64 * MOS];  // merge / out-staging (17.4 KB)
  __shared__ float lbuf[64];

  const unsigned short* Qb = qvws + (size_t)(bh * 4096) * 64;
  const unsigned short* Vb = qvws + (size_t)MTOT * 512 + (size_t)(bh * 64) * 4096;

  bf16x8 aK[4][2];
  if (KWS) {
    const unsigned short* Kb = qvws + (size_t)2 * MTOT * 512 + (size_t)(bh * 4096) * 64;
#pragma unroll
    for (int sub = 0; sub < 4; ++sub)
#pragma unroll
      for (int s = 0; s < 2; ++s)
        aK[sub][s] = *(const bf16x8*)(Kb + (size_t)(i0 + sub * 16 + n) * 64 + s * 32 + q * 8);
  } else {
    // Fallback: compute 64-row K tile; wave w does subs {2w, 2w+1}; via mO-as-LDS.
    unsigned short* Ks = (unsigned short*)mO;
    f32x4 ka[2][4] = {};
    for (int kk = 0; kk < 512; kk += 32) {
      bf16x8 a0 = ld8f32_bf16(mf + (size_t)(b_ * 4096 + i0 + (2 * w + 0) * 16 + n) * 512 + kk + q * 8);
      bf16x8 a1 = ld8f32_bf16(mf + (size_t)(b_ * 4096 + i0 + (2 * w + 1) * 16 + n) * 512 + kk + q * 8);
#pragma unroll
      for (int t = 0; t < 4; ++t) {
        bf16x8 bw = ld8f32_bf16(Wv + (size_t)(h * 64 + t * 16 + n) * 512 + kk + q * 8);
        ka[0][t] = __builtin_amdgcn_mfma_f32_16x16x32_bf16(a0, bw, ka[0][t], 0, 0, 0);
        ka[1][t] = __builtin_amdgcn_mfma_f32_16x16x32_bf16(a1, bw, ka[1][t], 0, 0, 0);
      }
    }
#pragma unroll
    for (int sl = 0; sl < 2; ++sl)
#pragma unroll
      for (int t = 0; t < 4; ++t) {
        const float bias = bv[h * 64 + t * 16 + n];
#pragma unroll
        for (int r = 0; r < 4; ++r)
          Ks[((2 * w + sl) * 16 + q * 4 + r) * LDP + t * 16 + n] =
              tb((ka[sl][t][r] + bias) * SC);
      }
    __syncthreads();
#pragma unroll
    for (int sub = 0; sub < 4; ++sub)
#pragma unroll
      for (int s = 0; s < 2; ++s)
        aK[sub][s] = *(const bf16x8*)(&Ks[(sub * 16 + n) * LDP + s * 32 + q * 8]);
    __syncthreads();
  }

  f32x4 o[4][4] = {};
  f32x4 lacc[4] = {};
  const bf16x8 ones = {(short)0x3F80, (short)0x3F80, (short)0x3F80, (short)0x3F80,
                       (short)0x3F80, (short)0x3F80, (short)0x3F80, (short)0x3F80};
  const int jbase = w * 2048;

  bf16x8 bqA[4][2], bqB[4][2], bvv[4][2];
  // Preload iteration 0.
#pragma unroll
  for (int jt = 0; jt < 4; ++jt)
#pragma unroll
    for (int s = 0; s < 2; ++s)
      bqA[jt][s] = *(const bf16x8*)(Qb + (size_t)(jbase + jt * 16 + n) * 64 + s * 32 + q * 8);
#pragma unroll
  for (int t = 0; t < 4; ++t)
#pragma unroll
    for (int s = 0; s < 2; ++s) {
      const unsigned short* p0 = Vb + (size_t)(t * 16 + n) * 4096 + jbase + 32 * s + 4 * q;
      bvv[t][s] = comb64(*(const uint2*)p0, *(const uint2*)(p0 + 16));
    }

  auto body = [&](bf16x8 (&bqc)[4][2], bf16x8 (&bqn)[4][2], int jn) {
    // Issue next iteration's bq immediately (double-buffered).
#pragma unroll
    for (int jt = 0; jt < 4; ++jt)
#pragma unroll
      for (int s = 0; s < 2; ++s)
        bqn[jt][s] = *(const bf16x8*)(Qb + (size_t)(jn + jt * 16 + n) * 64 + s * 32 + q * 8);

#pragma unroll
    for (int sub = 0; sub < 4; ++sub) {
      // Transposed scores: lane (n,q) reg r = S[j=jt*16+q*4+r][i=sub*16+n].
      f32x4 c[4] = {};
#pragma unroll
      for (int jt = 0; jt < 4; ++jt)
#pragma unroll
        for (int s = 0; s < 2; ++s)
          c[jt] = __builtin_amdgcn_mfma_f32_16x16x32_bf16(bqc[jt][s], aK[sub][s], c[jt], 0, 0, 0);
      // exp2 + in-register pack into PV A-frags under pi_s (no LDS!).
      bf16x8 pa[2];
#pragma unroll
      for (int s = 0; s < 2; ++s) {
        union { unsigned int u[4]; bf16x8 v; } p;
        p.u[0] = pkt(EXP2F(c[2 * s][0]), EXP2F(c[2 * s][1]));
        p.u[1] = pkt(EXP2F(c[2 * s][2]), EXP2F(c[2 * s][3]));
        p.u[2] = pkt(EXP2F(c[2 * s + 1][0]), EXP2F(c[2 * s + 1][1]));
        p.u[3] = pkt(EXP2F(c[2 * s + 1][2]), EXP2F(c[2 * s + 1][3]));
        pa[s] = p.v;
      }
#pragma unroll
      for (int s = 0; s < 2; ++s) {
        lacc[sub] = __builtin_amdgcn_mfma_f32_16x16x32_bf16(pa[s], ones, lacc[sub], 0, 0, 0);
#pragma unroll
        for (int t = 0; t < 4; ++t)
          o[sub][t] = __builtin_amdgcn_mfma_f32_16x16x32_bf16(pa[s], bvv[t][s], o[sub][t], 0, 0, 0);
      }
    }
    // Issue next iteration's bvv (regs now dead).
#pragma unroll
    for (int t = 0; t < 4; ++t)
#pragma unroll
      for (int s = 0; s < 2; ++s) {
        const unsigned short* p0 = Vb + (size_t)(t * 16 + n) * 4096 + jn + 32 * s + 4 * q;
        bvv[t][s] = comb64(*(const uint2*)p0, *(const uint2*)(p0 + 16));
      }
  };

  for (int it = 0; it < 32; it += 2) {
    body(bqA, bqB, jbase + ((it + 1) & 31) * 64);
    body(bqB, bqA, jbase + ((it + 2) & 31) * 64);
  }

  // ---- merge the two j-halves (f32, exact) + coalesced epilogue ----
  __syncthreads();
  const int eb = w ? 0 : 32, es0 = w ? 0 : 2;   // rows/subs I export
  const int kb = w ? 32 : 0, ks0 = w ? 2 : 0;   // rows/subs I keep
#pragma unroll
  for (int sl = 0; sl < 2; ++sl) {
    const int sub = es0 + sl;
#pragma unroll
    for (int t = 0; t < 4; ++t)
#pragma unroll
      for (int r = 0; r < 4; ++r)
        mO[(eb + sl * 16 + q * 4 + r) * MOS + t * 16 + n] = o[sub][t][r];
    if (n == 0)
#pragma unroll
      for (int r = 0; r < 4; ++r)
        lbuf[eb + sl * 16 + q * 4 + r] = lacc[sub][r];
  }
  __syncthreads();
#pragma unroll
  for (int sl = 0; sl < 2; ++sl) {
    const int sub = ks0 + sl;
    float li[4];
#pragma unroll
    for (int r = 0; r < 4; ++r)
      li[r] = 1.0f / (lacc[sub][r] + lbuf[kb + sl * 16 + q * 4 + r]);
#pragma unroll
    for (int t = 0; t < 4; ++t)
#pragma unroll
      for (int r = 0; r < 4; ++r) {
        const int mrow = kb + sl * 16 + q * 4 + r;
        const int mcol = t * 16 + n;
        mO[mrow * MOS + mcol] = (o[sub][t][r] + mO[mrow * MOS + mcol]) * li[r];
      }
  }
  __syncthreads();
  // Coalesced f32x4 out stores: 2 threads per row, 128B each.
  const int orow = threadIdx.x >> 1, ohalf = (threadIdx.x & 1) * 32;
  const size_t obase = (size_t)(b_ * 4096 + i0 + orow) * 512 + h * 64 + ohalf;
#pragma unroll
  for (int c4 = 0; c4 < 8; ++c4) {
    f32x4 v = *(const f32x4*)(&mO[orow * MOS + ohalf + c4 * 4]);
    f32x4 m = *(const f32x4*)(mf + obase + c4 * 4);
    *(f32x4*)(out + obase + c4 * 4) = v + m;
  }
}

extern "C" void kernel_launch(void* const* d_in, const int* in_sizes, int n_in,
                              void* d_out, int out_size, void* d_ws, size_t ws_size,
                              hipStream_t stream) {
  const float* mf = (const float*)d_in[0];  // (2,4096,512) f32
  const float* Wc = (const float*)d_in[1];  // (1024,512) f32
  const float* bc = (const float*)d_in[2];  // (1024,) f32
  const float* Wv = (const float*)d_in[3];  // (512,512) f32
  const float* bv = (const float*)d_in[4];  // (512,) f32
  float* out = (float*)d_out;
  unsigned short* ws = (unsigned short*)d_ws;

  const bool kws = ws_size >= (size_t)3 * MTOT * 512 * 2;  // Q+V^T+K bf16 = 24 MiB
  const int nct = kws ? 12 : 8;

  gemm_qvk<<<64 * nct, 256, 0, stream>>>(mf, Wc, bc, Wv, bv, ws, nct);
  if (kws)
    attn_kernel<true><<<1024, 128, 0, stream>>>(ws, mf, Wv, bv, out);
  else
    attn_kernel<false><<<1024, 128, 0, stream>>>(ws, mf, Wv, bv, out);
}